// Round 1
// baseline (1586.434 us; speedup 1.0000x reference)
//
#include <hip/hip_runtime.h>
#include <math.h>

#define PP 3
#define HH 4
#define DD 32
#define FF 128   // H*D
#define INF_ 128 // input feature dim
#define NEG_SLOPE 0.2f

// K1: feat[p] = h @ W[p]; also el = sum(feat*al,-1), er = sum(feat*ar,-1)
// one wave per (node, path); lane l owns output dims l and l+64
__global__ void k1_gemm(const float* __restrict__ h, const float* __restrict__ W,
                        const float* __restrict__ al, const float* __restrict__ ar,
                        float* __restrict__ feat, float* __restrict__ el,
                        float* __restrict__ er, int N) {
    __shared__ float hrow[4][INF_];
    int w = threadIdx.x >> 6, l = threadIdx.x & 63;
    int n = blockIdx.x * 4 + w;
    int p = blockIdx.y;
    if (n >= N) return;
    hrow[w][l]      = h[(size_t)n * INF_ + l];
    hrow[w][l + 64] = h[(size_t)n * INF_ + l + 64];
    __syncthreads();
    const float* Wp = W + (size_t)p * INF_ * FF;
    float acc0 = 0.f, acc1 = 0.f;
    for (int k = 0; k < INF_; ++k) {
        float hk = hrow[w][k];
        acc0 = fmaf(hk, Wp[k * FF + l], acc0);
        acc1 = fmaf(hk, Wp[k * FF + l + 64], acc1);
    }
    size_t fb = ((size_t)p * N + n) * FF;
    feat[fb + l]      = acc0;
    feat[fb + l + 64] = acc1;
    int h0 = l >> 5, d0 = l & 31;
    float pl0 = acc0 * al[(p * HH + h0) * DD + d0];
    float pl1 = acc1 * al[(p * HH + h0 + 2) * DD + d0];
    float pr0 = acc0 * ar[(p * HH + h0) * DD + d0];
    float pr1 = acc1 * ar[(p * HH + h0 + 2) * DD + d0];
    for (int off = 16; off >= 1; off >>= 1) {
        pl0 += __shfl_xor(pl0, off);
        pl1 += __shfl_xor(pl1, off);
        pr0 += __shfl_xor(pr0, off);
        pr1 += __shfl_xor(pr1, off);
    }
    if (d0 == 0) {
        size_t eb = ((size_t)p * N + n) * HH;
        el[eb + h0]     = pl0;
        el[eb + h0 + 2] = pl1;
        er[eb + h0]     = pr0;
        er[eb + h0 + 2] = pr1;
    }
}

// K2: histogram of dst degrees
__global__ void k2_hist(const int* __restrict__ dst, int* __restrict__ counts,
                        int E, int N) {
    int p = blockIdx.y;
    int i = blockIdx.x * 256 + threadIdx.x;
    if (i < E) atomicAdd(&counts[(size_t)p * N + dst[(size_t)p * E + i]], 1);
}

// K3: exclusive prefix sum over counts -> offs (N+1), cursor copy. one block per path.
__global__ __launch_bounds__(1024) void k3_scan(const int* __restrict__ counts,
                                                int* __restrict__ offs,
                                                int* __restrict__ cursor, int N) {
    __shared__ int lds[1024];
    int p = blockIdx.x;
    int t = threadIdx.x;
    int chunk = (N + 1023) / 1024;
    int base = t * chunk;
    int end = base + chunk; if (end > N) end = N; if (base > N) base = N;
    int s = 0;
    for (int i = base; i < end; ++i) s += counts[(size_t)p * N + i];
    lds[t] = s;
    __syncthreads();
    for (int off = 1; off < 1024; off <<= 1) {
        int v = (t >= off) ? lds[t - off] : 0;
        __syncthreads();
        lds[t] += v;
        __syncthreads();
    }
    int run = lds[t] - s;  // exclusive prefix for this thread
    for (int i = base; i < end; ++i) {
        offs[(size_t)p * (N + 1) + i] = run;
        cursor[(size_t)p * N + i] = run;
        run += counts[(size_t)p * N + i];
    }
    if (t == 0) offs[(size_t)p * (N + 1) + N] = lds[1023];
}

// K4: scatter src ids into CSR slots
__global__ void k4_scatter(const int* __restrict__ src, const int* __restrict__ dst,
                           int* __restrict__ cursor, int* __restrict__ csr,
                           int E, int N) {
    int p = blockIdx.y;
    int i = blockIdx.x * 256 + threadIdx.x;
    if (i < E) {
        int dv = dst[(size_t)p * E + i];
        int pos = atomicAdd(&cursor[(size_t)p * N + dv], 1);
        csr[(size_t)p * E + pos] = src[(size_t)p * E + i];
    }
}

// K5: per-(node,path) softmax-weighted aggregation; one wave per (node,path)
__global__ void k5_aggregate(const float* __restrict__ feat, const float* __restrict__ el,
                             const float* __restrict__ er, const float* __restrict__ bias,
                             const int* __restrict__ offs, const int* __restrict__ csr,
                             float* __restrict__ z, int N, int E) {
    int w = threadIdx.x >> 6, l = threadIdx.x & 63;
    int n = blockIdx.x * 4 + w;
    int p = blockIdx.y;
    if (n >= N) return;
    int h0 = l >> 5;
    size_t eb = ((size_t)p * N + n) * HH;
    float r0 = er[eb + h0], r1 = er[eb + h0 + 2];
    int j0 = offs[(size_t)p * (N + 1) + n];
    int j1 = offs[(size_t)p * (N + 1) + n + 1];
    const int* cs = csr + (size_t)p * E;
    const float* elp = el + (size_t)p * N * HH;
    float m0 = -INFINITY, m1 = -INFINITY, sum0 = 0.f, sum1 = 0.f;
    for (int j = j0; j < j1; ++j) {
        int sn = cs[j];
        float e0 = elp[(size_t)sn * HH + h0] + r0;
        e0 = e0 > 0.f ? e0 : NEG_SLOPE * e0;
        float e1 = elp[(size_t)sn * HH + h0 + 2] + r1;
        e1 = e1 > 0.f ? e1 : NEG_SLOPE * e1;
        float nm0 = fmaxf(m0, e0);
        sum0 = sum0 * __expf(m0 - nm0) + __expf(e0 - nm0);
        m0 = nm0;
        float nm1 = fmaxf(m1, e1);
        sum1 = sum1 * __expf(m1 - nm1) + __expf(e1 - nm1);
        m1 = nm1;
    }
    float inv0 = 1.f / sum0, inv1 = 1.f / sum1;
    const float* fp = feat + (size_t)p * N * FF;
    float acc0 = 0.f, acc1 = 0.f;
    for (int j = j0; j < j1; ++j) {
        int sn = cs[j];
        float e0 = elp[(size_t)sn * HH + h0] + r0;
        e0 = e0 > 0.f ? e0 : NEG_SLOPE * e0;
        float e1 = elp[(size_t)sn * HH + h0 + 2] + r1;
        e1 = e1 > 0.f ? e1 : NEG_SLOPE * e1;
        float w0 = __expf(e0 - m0) * inv0;
        float w1 = __expf(e1 - m1) * inv1;
        acc0 = fmaf(w0, fp[(size_t)sn * FF + l], acc0);
        acc1 = fmaf(w1, fp[(size_t)sn * FF + l + 64], acc1);
    }
    float z0 = acc0 + bias[p * FF + l];
    float z1 = acc1 + bias[p * FF + l + 64];
    z0 = z0 > 0.f ? z0 : expm1f(z0);
    z1 = z1 > 0.f ? z1 : expm1f(z1);
    size_t zb = ((size_t)p * N + n) * FF;
    z[zb + l]      = z0;
    z[zb + l + 64] = z1;
}

// K6: s[n,p] = tanh(z @ W1 + b1) @ W2, block-partial sums over n
__global__ void k6_semantic(const float* __restrict__ z, const float* __restrict__ W1,
                            const float* __restrict__ b1, const float* __restrict__ W2,
                            float* __restrict__ partials, int N) {
    __shared__ float zrow[4][FF];
    __shared__ float wsum[4];
    int w = threadIdx.x >> 6, l = threadIdx.x & 63;
    int n = blockIdx.x * 4 + w;
    int p = blockIdx.y;
    bool valid = n < N;
    if (valid) {
        size_t zb = ((size_t)p * N + n) * FF;
        zrow[w][l]      = z[zb + l];
        zrow[w][l + 64] = z[zb + l + 64];
    }
    __syncthreads();
    float a0 = 0.f, a1 = 0.f;
    for (int k = 0; k < FF; ++k) {
        float zk = zrow[w][k];
        a0 = fmaf(zk, W1[k * FF + l], a0);
        a1 = fmaf(zk, W1[k * FF + l + 64], a1);
    }
    float t0 = tanhf(a0 + b1[l]);
    float t1 = tanhf(a1 + b1[l + 64]);
    float sres = t0 * W2[l] + t1 * W2[l + 64];
    for (int off = 32; off >= 1; off >>= 1) sres += __shfl_xor(sres, off);
    if (l == 0) wsum[w] = valid ? sres : 0.f;
    __syncthreads();
    if (threadIdx.x == 0)
        partials[(size_t)p * gridDim.x + blockIdx.x] = wsum[0] + wsum[1] + wsum[2] + wsum[3];
}

// K7: reduce partials -> w[p] mean -> beta softmax. one block, 3 waves.
__global__ void k7_beta(const float* __restrict__ partials, float* __restrict__ beta,
                        int nblk, int N) {
    __shared__ float wl[3];
    int p = threadIdx.x >> 6, l = threadIdx.x & 63;
    float s = 0.f;
    for (int i = l; i < nblk; i += 64) s += partials[(size_t)p * nblk + i];
    for (int off = 32; off >= 1; off >>= 1) s += __shfl_xor(s, off);
    if (l == 0) wl[p] = s / (float)N;
    __syncthreads();
    if (threadIdx.x == 0) {
        float m = fmaxf(wl[0], fmaxf(wl[1], wl[2]));
        float e0 = __expf(wl[0] - m), e1 = __expf(wl[1] - m), e2 = __expf(wl[2] - m);
        float inv = 1.f / (e0 + e1 + e2);
        beta[0] = e0 * inv; beta[1] = e1 * inv; beta[2] = e2 * inv;
    }
}

// K8: out[n,:] = sum_p beta[p] * z[p][n,:]
__global__ void k8_combine(const float* __restrict__ z, const float* __restrict__ beta,
                           float* __restrict__ out, int N) {
    size_t i = (size_t)blockIdx.x * 256 + threadIdx.x;
    size_t tot = (size_t)N * FF;
    if (i < tot) {
        float b0 = beta[0], b1 = beta[1], b2 = beta[2];
        out[i] = b0 * z[i] + b1 * z[tot + i] + b2 * z[2 * tot + i];
    }
}

extern "C" void kernel_launch(void* const* d_in, const int* in_sizes, int n_in,
                              void* d_out, int out_size, void* d_ws, size_t ws_size,
                              hipStream_t stream) {
    const float* h    = (const float*)d_in[0];
    const float* W    = (const float*)d_in[1];
    const float* al   = (const float*)d_in[2];
    const float* ar   = (const float*)d_in[3];
    const float* bias = (const float*)d_in[4];
    const float* W1   = (const float*)d_in[5];
    const float* b1   = (const float*)d_in[6];
    const float* W2   = (const float*)d_in[7];
    const int*   src  = (const int*)d_in[8];
    const int*   dst  = (const int*)d_in[9];
    float* out = (float*)d_out;

    int N = in_sizes[0] / INF_;
    int E = in_sizes[8] / PP;

    // workspace layout
    char* ws = (char*)d_ws;
    size_t off = 0;
    auto take = [&](size_t bytes) -> void* {
        off = (off + 255) & ~(size_t)255;
        void* ptr = ws + off;
        off += bytes;
        return ptr;
    };
    float* feat     = (float*)take((size_t)PP * N * FF * sizeof(float));
    float* z        = (float*)take((size_t)PP * N * FF * sizeof(float));
    float* el       = (float*)take((size_t)PP * N * HH * sizeof(float));
    float* er       = (float*)take((size_t)PP * N * HH * sizeof(float));
    int*   counts   = (int*)take((size_t)PP * N * sizeof(int));
    int*   offs     = (int*)take((size_t)PP * (N + 1) * sizeof(int));
    int*   cursor   = (int*)take((size_t)PP * N * sizeof(int));
    int*   csr      = (int*)take((size_t)PP * E * sizeof(int));
    int    nblk     = (N + 3) / 4;
    float* partials = (float*)take((size_t)PP * nblk * sizeof(float));
    float* betap    = (float*)take(16);
    (void)ws_size; (void)n_in; (void)out_size;

    hipMemsetAsync(counts, 0, (size_t)PP * N * sizeof(int), stream);

    dim3 gNode(nblk, PP);
    dim3 gEdge((E + 255) / 256, PP);

    k1_gemm<<<gNode, 256, 0, stream>>>(h, W, al, ar, feat, el, er, N);
    k2_hist<<<gEdge, 256, 0, stream>>>(dst, counts, E, N);
    k3_scan<<<PP, 1024, 0, stream>>>(counts, offs, cursor, N);
    k4_scatter<<<gEdge, 256, 0, stream>>>(src, dst, cursor, csr, E, N);
    k5_aggregate<<<gNode, 256, 0, stream>>>(feat, el, er, bias, offs, csr, z, N, E);
    k6_semantic<<<gNode, 256, 0, stream>>>(z, W1, b1, W2, partials, N);
    k7_beta<<<1, 192, 0, stream>>>(partials, betap, nblk, N);
    k8_combine<<<(int)(((size_t)N * FF + 255) / 256), 256, 0, stream>>>(z, betap, out, N);
}

// Round 2
// 1315.930 us; speedup vs baseline: 1.2056x; 1.2056x over previous
//
#include <hip/hip_runtime.h>
#include <math.h>

#define PP 3
#define HH 4
#define DD 32
#define FF 128   // H*D
#define INF_ 128 // input feature dim
#define NEG_SLOPE 0.2f

// K1: feat[p] = h @ W[p]; el = sum(feat*al,-1), er = sum(feat*ar,-1)
// 4 waves/block, 8 nodes/wave, lane l owns cols 2l,2l+1.
// h rows read via wave-uniform (scalar) loads; W streamed as float2 (L1/L2-cached).
__global__ __launch_bounds__(256) void k1_gemm(const float* __restrict__ h, const float* __restrict__ W,
                        const float* __restrict__ al, const float* __restrict__ ar,
                        float* __restrict__ feat, float* __restrict__ el,
                        float* __restrict__ er, int N) {
    int l = threadIdx.x & 63;
    int wu = __builtin_amdgcn_readfirstlane(threadIdx.x >> 6);
    int p = blockIdx.y;
    int nbase = blockIdx.x * 32 + wu * 8;
    if (nbase >= N) return;
    int nv = N - nbase; if (nv > 8) nv = 8;
    const float* Wp = W + (size_t)p * INF_ * FF;
    const float* hb = h + (size_t)nbase * INF_;
    int c0 = 2 * l;
    float2 acc[8];
#pragma unroll
    for (int i = 0; i < 8; ++i) acc[i] = make_float2(0.f, 0.f);

    if (nv == 8) {
        for (int k = 0; k < INF_; k += 4) {
            float2 wv0 = *(const float2*)&Wp[(k + 0) * FF + c0];
            float2 wv1 = *(const float2*)&Wp[(k + 1) * FF + c0];
            float2 wv2 = *(const float2*)&Wp[(k + 2) * FF + c0];
            float2 wv3 = *(const float2*)&Wp[(k + 3) * FF + c0];
#pragma unroll
            for (int nn = 0; nn < 8; ++nn) {
                float4 hv = *(const float4*)&hb[nn * INF_ + k];   // wave-uniform -> s_load
                acc[nn].x = fmaf(hv.x, wv0.x, acc[nn].x);
                acc[nn].y = fmaf(hv.x, wv0.y, acc[nn].y);
                acc[nn].x = fmaf(hv.y, wv1.x, acc[nn].x);
                acc[nn].y = fmaf(hv.y, wv1.y, acc[nn].y);
                acc[nn].x = fmaf(hv.z, wv2.x, acc[nn].x);
                acc[nn].y = fmaf(hv.z, wv2.y, acc[nn].y);
                acc[nn].x = fmaf(hv.w, wv3.x, acc[nn].x);
                acc[nn].y = fmaf(hv.w, wv3.y, acc[nn].y);
            }
        }
    } else {
        for (int k = 0; k < INF_; k += 4) {
            float2 wv0 = *(const float2*)&Wp[(k + 0) * FF + c0];
            float2 wv1 = *(const float2*)&Wp[(k + 1) * FF + c0];
            float2 wv2 = *(const float2*)&Wp[(k + 2) * FF + c0];
            float2 wv3 = *(const float2*)&Wp[(k + 3) * FF + c0];
            for (int nn = 0; nn < nv; ++nn) {
                float4 hv = *(const float4*)&hb[nn * INF_ + k];
                acc[nn].x = fmaf(hv.x, wv0.x, acc[nn].x);
                acc[nn].y = fmaf(hv.x, wv0.y, acc[nn].y);
                acc[nn].x = fmaf(hv.y, wv1.x, acc[nn].x);
                acc[nn].y = fmaf(hv.y, wv1.y, acc[nn].y);
                acc[nn].x = fmaf(hv.z, wv2.x, acc[nn].x);
                acc[nn].y = fmaf(hv.z, wv2.y, acc[nn].y);
                acc[nn].x = fmaf(hv.w, wv3.x, acc[nn].x);
                acc[nn].y = fmaf(hv.w, wv3.y, acc[nn].y);
            }
        }
    }

    int hd = l >> 4;
    int d0 = (2 * l) & 31;
    float2 alv = *(const float2*)&al[(p * HH + hd) * DD + d0];
    float2 arv = *(const float2*)&ar[(p * HH + hd) * DD + d0];
#pragma unroll
    for (int nn = 0; nn < 8; ++nn) {
        if (nn >= nv) break;
        int n = nbase + nn;
        size_t fb = ((size_t)p * N + n) * FF;
        *(float2*)&feat[fb + c0] = acc[nn];
        float pl = acc[nn].x * alv.x + acc[nn].y * alv.y;
        float pr = acc[nn].x * arv.x + acc[nn].y * arv.y;
        for (int off = 8; off >= 1; off >>= 1) {
            pl += __shfl_xor(pl, off);
            pr += __shfl_xor(pr, off);
        }
        if ((l & 15) == 0) {
            size_t eb = ((size_t)p * N + n) * HH + hd;
            el[eb] = pl;
            er[eb] = pr;
        }
    }
}

// K2: histogram of dst degrees
__global__ void k2_hist(const int* __restrict__ dst, int* __restrict__ counts,
                        int E, int N) {
    int p = blockIdx.y;
    int i = blockIdx.x * 256 + threadIdx.x;
    if (i < E) atomicAdd(&counts[(size_t)p * N + dst[(size_t)p * E + i]], 1);
}

// K3: exclusive prefix sum over counts -> offs (N+1), cursor copy. one block per path.
__global__ __launch_bounds__(1024) void k3_scan(const int* __restrict__ counts,
                                                int* __restrict__ offs,
                                                int* __restrict__ cursor, int N) {
    __shared__ int lds[1024];
    int p = blockIdx.x;
    int t = threadIdx.x;
    int chunk = (N + 1023) / 1024;
    int base = t * chunk;
    int end = base + chunk; if (end > N) end = N; if (base > N) base = N;
    int s = 0;
    for (int i = base; i < end; ++i) s += counts[(size_t)p * N + i];
    lds[t] = s;
    __syncthreads();
    for (int off = 1; off < 1024; off <<= 1) {
        int v = (t >= off) ? lds[t - off] : 0;
        __syncthreads();
        lds[t] += v;
        __syncthreads();
    }
    int run = lds[t] - s;  // exclusive prefix for this thread
    for (int i = base; i < end; ++i) {
        offs[(size_t)p * (N + 1) + i] = run;
        cursor[(size_t)p * N + i] = run;
        run += counts[(size_t)p * N + i];
    }
    if (t == 0) offs[(size_t)p * (N + 1) + N] = lds[1023];
}

// K4: scatter src ids into CSR slots
__global__ void k4_scatter(const int* __restrict__ src, const int* __restrict__ dst,
                           int* __restrict__ cursor, int* __restrict__ csr,
                           int E, int N) {
    int p = blockIdx.y;
    int i = blockIdx.x * 256 + threadIdx.x;
    if (i < E) {
        int dv = dst[(size_t)p * E + i];
        int pos = atomicAdd(&cursor[(size_t)p * N + dv], 1);
        csr[(size_t)p * E + pos] = src[(size_t)p * E + i];
    }
}

// K5: per-(node,path) single-pass softmax aggregation. No max subtraction:
// scores bounded (|el+er| small by construction), exp(e) safe in fp32.
// Lane l owns cols 2l,2l+1 (head hd=l>>4); one float2 feat gather per edge.
__global__ __launch_bounds__(256) void k5_aggregate(const float* __restrict__ feat, const float* __restrict__ el,
                             const float* __restrict__ er, const float* __restrict__ bias,
                             const int* __restrict__ offs, const int* __restrict__ csr,
                             float* __restrict__ z, int N, int E) {
    int w = threadIdx.x >> 6, l = threadIdx.x & 63;
    int n = blockIdx.x * 4 + w;
    int p = blockIdx.y;
    if (n >= N) return;
    int hd = l >> 4;
    int c0 = 2 * l;
    size_t eb = ((size_t)p * N + n) * HH;
    float r = er[eb + hd];
    int j0 = offs[(size_t)p * (N + 1) + n];
    int j1 = offs[(size_t)p * (N + 1) + n + 1];
    const int* cs = csr + (size_t)p * E;
    const float* elp = el + (size_t)p * N * HH;
    const float* fp = feat + (size_t)p * N * FF;
    float acc0 = 0.f, acc1 = 0.f, sumw = 0.f;
    for (int base = j0; base < j1; base += 64) {
        int rem = j1 - base;
        int cnt = rem > 64 ? 64 : rem;
        int mysn = (l < cnt) ? cs[base + l] : 0;   // coalesced batch load of edge srcs
        int tt = 0;
        for (; tt + 2 <= cnt; tt += 2) {
            int sa = __shfl(mysn, tt);
            int sb = __shfl(mysn, tt + 1);
            float ea = elp[(size_t)sa * HH + hd] + r;
            float eb2 = elp[(size_t)sb * HH + hd] + r;
            float2 fa = *(const float2*)&fp[(size_t)sa * FF + c0];
            float2 fb = *(const float2*)&fp[(size_t)sb * FF + c0];
            ea = fmaxf(ea, NEG_SLOPE * ea);
            eb2 = fmaxf(eb2, NEG_SLOPE * eb2);
            float wa = __expf(ea);
            float wb = __expf(eb2);
            acc0 = fmaf(wa, fa.x, acc0);
            acc1 = fmaf(wa, fa.y, acc1);
            sumw += wa;
            acc0 = fmaf(wb, fb.x, acc0);
            acc1 = fmaf(wb, fb.y, acc1);
            sumw += wb;
        }
        if (tt < cnt) {
            int sa = __shfl(mysn, tt);
            float ea = elp[(size_t)sa * HH + hd] + r;
            float2 fa = *(const float2*)&fp[(size_t)sa * FF + c0];
            ea = fmaxf(ea, NEG_SLOPE * ea);
            float wa = __expf(ea);
            acc0 = fmaf(wa, fa.x, acc0);
            acc1 = fmaf(wa, fa.y, acc1);
            sumw += wa;
        }
    }
    float inv = 1.f / sumw;   // self-loops guarantee sumw > 0
    float2 bv = *(const float2*)&bias[p * FF + c0];
    float z0 = acc0 * inv + bv.x;
    float z1 = acc1 * inv + bv.y;
    z0 = z0 > 0.f ? z0 : __expf(z0) - 1.f;
    z1 = z1 > 0.f ? z1 : __expf(z1) - 1.f;
    size_t zb = ((size_t)p * N + n) * FF;
    *(float2*)&z[zb + c0] = make_float2(z0, z1);
}

// K6: s[n,p] = tanh(z @ W1 + b1) @ W2; same 8-nodes/wave register tiling.
__global__ __launch_bounds__(256) void k6_semantic(const float* __restrict__ z, const float* __restrict__ W1,
                            const float* __restrict__ b1, const float* __restrict__ W2,
                            float* __restrict__ partials, int N) {
    __shared__ float wsum[4];
    int t = threadIdx.x;
    int l = t & 63;
    int wu = __builtin_amdgcn_readfirstlane(t >> 6);
    int p = blockIdx.y;
    int nbase = blockIdx.x * 32 + wu * 8;
    int c0 = 2 * l;
    float ssum = 0.f;
    if (nbase < N) {
        int nv = N - nbase; if (nv > 8) nv = 8;
        const float* zb = z + ((size_t)p * N + nbase) * FF;
        float2 acc[8];
#pragma unroll
        for (int i = 0; i < 8; ++i) acc[i] = make_float2(0.f, 0.f);
        if (nv == 8) {
            for (int k = 0; k < FF; k += 4) {
                float2 wv0 = *(const float2*)&W1[(k + 0) * FF + c0];
                float2 wv1 = *(const float2*)&W1[(k + 1) * FF + c0];
                float2 wv2 = *(const float2*)&W1[(k + 2) * FF + c0];
                float2 wv3 = *(const float2*)&W1[(k + 3) * FF + c0];
#pragma unroll
                for (int nn = 0; nn < 8; ++nn) {
                    float4 zv = *(const float4*)&zb[nn * FF + k];   // wave-uniform -> s_load
                    acc[nn].x = fmaf(zv.x, wv0.x, acc[nn].x);
                    acc[nn].y = fmaf(zv.x, wv0.y, acc[nn].y);
                    acc[nn].x = fmaf(zv.y, wv1.x, acc[nn].x);
                    acc[nn].y = fmaf(zv.y, wv1.y, acc[nn].y);
                    acc[nn].x = fmaf(zv.z, wv2.x, acc[nn].x);
                    acc[nn].y = fmaf(zv.z, wv2.y, acc[nn].y);
                    acc[nn].x = fmaf(zv.w, wv3.x, acc[nn].x);
                    acc[nn].y = fmaf(zv.w, wv3.y, acc[nn].y);
                }
            }
        } else {
            for (int k = 0; k < FF; k += 4) {
                float2 wv0 = *(const float2*)&W1[(k + 0) * FF + c0];
                float2 wv1 = *(const float2*)&W1[(k + 1) * FF + c0];
                float2 wv2 = *(const float2*)&W1[(k + 2) * FF + c0];
                float2 wv3 = *(const float2*)&W1[(k + 3) * FF + c0];
                for (int nn = 0; nn < nv; ++nn) {
                    float4 zv = *(const float4*)&zb[nn * FF + k];
                    acc[nn].x = fmaf(zv.x, wv0.x, acc[nn].x);
                    acc[nn].y = fmaf(zv.x, wv0.y, acc[nn].y);
                    acc[nn].x = fmaf(zv.y, wv1.x, acc[nn].x);
                    acc[nn].y = fmaf(zv.y, wv1.y, acc[nn].y);
                    acc[nn].x = fmaf(zv.z, wv2.x, acc[nn].x);
                    acc[nn].y = fmaf(zv.z, wv2.y, acc[nn].y);
                    acc[nn].x = fmaf(zv.w, wv3.x, acc[nn].x);
                    acc[nn].y = fmaf(zv.w, wv3.y, acc[nn].y);
                }
            }
        }
        float2 b1v = *(const float2*)&b1[c0];
        float2 w2v = *(const float2*)&W2[c0];
#pragma unroll
        for (int nn = 0; nn < 8; ++nn) {
            if (nn >= nv) break;
            float a0 = acc[nn].x + b1v.x;
            float a1 = acc[nn].y + b1v.y;
            // tanh(x) = 1 - 2/(exp(2x)+1)  (safe at +/-inf)
            float e0 = __expf(2.f * a0);
            float e1 = __expf(2.f * a1);
            float t0 = 1.f - 2.f * __builtin_amdgcn_rcpf(e0 + 1.f);
            float t1 = 1.f - 2.f * __builtin_amdgcn_rcpf(e1 + 1.f);
            ssum += t0 * w2v.x + t1 * w2v.y;
        }
    }
    for (int off = 32; off >= 1; off >>= 1) ssum += __shfl_xor(ssum, off);
    if (l == 0) wsum[wu] = ssum;
    __syncthreads();
    if (t == 0)
        partials[(size_t)p * gridDim.x + blockIdx.x] = wsum[0] + wsum[1] + wsum[2] + wsum[3];
}

// K7: reduce partials -> w[p] mean -> beta softmax. one block, 3 waves.
__global__ void k7_beta(const float* __restrict__ partials, float* __restrict__ beta,
                        int nblk, int N) {
    __shared__ float wl[3];
    int p = threadIdx.x >> 6, l = threadIdx.x & 63;
    float s = 0.f;
    for (int i = l; i < nblk; i += 64) s += partials[(size_t)p * nblk + i];
    for (int off = 32; off >= 1; off >>= 1) s += __shfl_xor(s, off);
    if (l == 0) wl[p] = s / (float)N;
    __syncthreads();
    if (threadIdx.x == 0) {
        float m = fmaxf(wl[0], fmaxf(wl[1], wl[2]));
        float e0 = __expf(wl[0] - m), e1 = __expf(wl[1] - m), e2 = __expf(wl[2] - m);
        float inv = 1.f / (e0 + e1 + e2);
        beta[0] = e0 * inv; beta[1] = e1 * inv; beta[2] = e2 * inv;
    }
}

// K8: out[n,:] = sum_p beta[p] * z[p][n,:]
__global__ void k8_combine(const float* __restrict__ z, const float* __restrict__ beta,
                           float* __restrict__ out, int N) {
    size_t i = (size_t)blockIdx.x * 256 + threadIdx.x;
    size_t tot = (size_t)N * FF;
    if (i < tot) {
        float b0 = beta[0], b1 = beta[1], b2 = beta[2];
        out[i] = b0 * z[i] + b1 * z[tot + i] + b2 * z[2 * tot + i];
    }
}

extern "C" void kernel_launch(void* const* d_in, const int* in_sizes, int n_in,
                              void* d_out, int out_size, void* d_ws, size_t ws_size,
                              hipStream_t stream) {
    const float* h    = (const float*)d_in[0];
    const float* W    = (const float*)d_in[1];
    const float* al   = (const float*)d_in[2];
    const float* ar   = (const float*)d_in[3];
    const float* bias = (const float*)d_in[4];
    const float* W1   = (const float*)d_in[5];
    const float* b1   = (const float*)d_in[6];
    const float* W2   = (const float*)d_in[7];
    const int*   src  = (const int*)d_in[8];
    const int*   dst  = (const int*)d_in[9];
    float* out = (float*)d_out;

    int N = in_sizes[0] / INF_;
    int E = in_sizes[8] / PP;

    char* ws = (char*)d_ws;
    size_t off = 0;
    auto take = [&](size_t bytes) -> void* {
        off = (off + 255) & ~(size_t)255;
        void* ptr = ws + off;
        off += bytes;
        return ptr;
    };
    float* feat     = (float*)take((size_t)PP * N * FF * sizeof(float));
    float* z        = (float*)take((size_t)PP * N * FF * sizeof(float));
    float* el       = (float*)take((size_t)PP * N * HH * sizeof(float));
    float* er       = (float*)take((size_t)PP * N * HH * sizeof(float));
    int*   counts   = (int*)take((size_t)PP * N * sizeof(int));
    int*   offs     = (int*)take((size_t)PP * (N + 1) * sizeof(int));
    int*   cursor   = (int*)take((size_t)PP * N * sizeof(int));
    int*   csr      = (int*)take((size_t)PP * E * sizeof(int));
    int    nblk32   = (N + 31) / 32;
    int    nblk4    = (N + 3) / 4;
    float* partials = (float*)take((size_t)PP * nblk32 * sizeof(float));
    float* betap    = (float*)take(16);
    (void)ws_size; (void)n_in; (void)out_size;

    hipMemsetAsync(counts, 0, (size_t)PP * N * sizeof(int), stream);

    dim3 gTile(nblk32, PP);
    dim3 gNode(nblk4, PP);
    dim3 gEdge((E + 255) / 256, PP);

    k1_gemm<<<gTile, 256, 0, stream>>>(h, W, al, ar, feat, el, er, N);
    k2_hist<<<gEdge, 256, 0, stream>>>(dst, counts, E, N);
    k3_scan<<<PP, 1024, 0, stream>>>(counts, offs, cursor, N);
    k4_scatter<<<gEdge, 256, 0, stream>>>(src, dst, cursor, csr, E, N);
    k5_aggregate<<<gNode, 256, 0, stream>>>(feat, el, er, bias, offs, csr, z, N, E);
    k6_semantic<<<gTile, 256, 0, stream>>>(z, W1, b1, W2, partials, N);
    k7_beta<<<1, 192, 0, stream>>>(partials, betap, nblk32, N);
    k8_combine<<<(int)(((size_t)N * FF + 255) / 256), 256, 0, stream>>>(z, betap, out, N);
}

// Round 3
// 892.984 us; speedup vs baseline: 1.7766x; 1.4736x over previous
//
#include <hip/hip_runtime.h>
#include <math.h>

#define PP 3
#define HH 4
#define DD 32
#define FF 128   // H*D
#define INF_ 128 // input feature dim
#define NEG_SLOPE 0.2f

// K1: feat[p] = h @ W[p]; el = sum(feat*al,-1), er = sum(feat*ar,-1)
// 4 waves/block, 8 nodes/wave, lane l owns cols 2l,2l+1.
// CRITICAL: acc[] must stay in VGPRs -> every index compile-time constant
// (full unroll, no variable-bound loops). Tail rows clamped to N-1 for loads,
// stores predicated.
__global__ __launch_bounds__(256) void k1_gemm(const float* __restrict__ h, const float* __restrict__ W,
                        const float* __restrict__ al, const float* __restrict__ ar,
                        float* __restrict__ feat, float* __restrict__ el,
                        float* __restrict__ er, int N) {
    int l = threadIdx.x & 63;
    int wu = __builtin_amdgcn_readfirstlane(threadIdx.x >> 6);
    int p = blockIdx.y;
    int nbase = blockIdx.x * 32 + wu * 8;
    if (nbase >= N) return;
    const float* Wp = W + (size_t)p * INF_ * FF;
    int c0 = 2 * l;
    // wave-uniform clamped row offsets (scalar regs)
    int maxoff = N - 1 - nbase;
    size_t roff[8];
#pragma unroll
    for (int nn = 0; nn < 8; ++nn)
        roff[nn] = (size_t)(nn < maxoff ? nn : maxoff) * INF_;
    const float* hb = h + (size_t)nbase * INF_;

    float2 acc[8];
#pragma unroll
    for (int i = 0; i < 8; ++i) acc[i] = make_float2(0.f, 0.f);

    for (int k = 0; k < INF_; k += 4) {
        float2 wv0 = *(const float2*)&Wp[(k + 0) * FF + c0];
        float2 wv1 = *(const float2*)&Wp[(k + 1) * FF + c0];
        float2 wv2 = *(const float2*)&Wp[(k + 2) * FF + c0];
        float2 wv3 = *(const float2*)&Wp[(k + 3) * FF + c0];
#pragma unroll
        for (int nn = 0; nn < 8; ++nn) {
            float4 hv = *(const float4*)&hb[roff[nn] + k];   // wave-uniform -> s_load
            acc[nn].x = fmaf(hv.x, wv0.x, acc[nn].x);
            acc[nn].y = fmaf(hv.x, wv0.y, acc[nn].y);
            acc[nn].x = fmaf(hv.y, wv1.x, acc[nn].x);
            acc[nn].y = fmaf(hv.y, wv1.y, acc[nn].y);
            acc[nn].x = fmaf(hv.z, wv2.x, acc[nn].x);
            acc[nn].y = fmaf(hv.z, wv2.y, acc[nn].y);
            acc[nn].x = fmaf(hv.w, wv3.x, acc[nn].x);
            acc[nn].y = fmaf(hv.w, wv3.y, acc[nn].y);
        }
    }

    int hd = l >> 4;
    int d0 = (2 * l) & 31;
    float2 alv = *(const float2*)&al[(p * HH + hd) * DD + d0];
    float2 arv = *(const float2*)&ar[(p * HH + hd) * DD + d0];
#pragma unroll
    for (int nn = 0; nn < 8; ++nn) {
        bool valid = nn <= maxoff;
        int n = nbase + nn;
        float pl = acc[nn].x * alv.x + acc[nn].y * alv.y;
        float pr = acc[nn].x * arv.x + acc[nn].y * arv.y;
        for (int off = 8; off >= 1; off >>= 1) {
            pl += __shfl_xor(pl, off);
            pr += __shfl_xor(pr, off);
        }
        if (valid) {
            size_t fb = ((size_t)p * N + n) * FF;
            *(float2*)&feat[fb + c0] = acc[nn];
            if ((l & 15) == 0) {
                size_t eb = ((size_t)p * N + n) * HH + hd;
                el[eb] = pl;
                er[eb] = pr;
            }
        }
    }
}

// K2: histogram of dst degrees
__global__ void k2_hist(const int* __restrict__ dst, int* __restrict__ counts,
                        int E, int N) {
    int p = blockIdx.y;
    int i = blockIdx.x * 256 + threadIdx.x;
    if (i < E) atomicAdd(&counts[(size_t)p * N + dst[(size_t)p * E + i]], 1);
}

// K3: exclusive prefix sum over counts -> offs (N+1), cursor copy. one block per path.
__global__ __launch_bounds__(1024) void k3_scan(const int* __restrict__ counts,
                                                int* __restrict__ offs,
                                                int* __restrict__ cursor, int N) {
    __shared__ int lds[1024];
    int p = blockIdx.x;
    int t = threadIdx.x;
    int chunk = (N + 1023) / 1024;
    int base = t * chunk;
    int end = base + chunk; if (end > N) end = N; if (base > N) base = N;
    int s = 0;
    for (int i = base; i < end; ++i) s += counts[(size_t)p * N + i];
    lds[t] = s;
    __syncthreads();
    for (int off = 1; off < 1024; off <<= 1) {
        int v = (t >= off) ? lds[t - off] : 0;
        __syncthreads();
        lds[t] += v;
        __syncthreads();
    }
    int run = lds[t] - s;  // exclusive prefix for this thread
    for (int i = base; i < end; ++i) {
        offs[(size_t)p * (N + 1) + i] = run;
        cursor[(size_t)p * N + i] = run;
        run += counts[(size_t)p * N + i];
    }
    if (t == 0) offs[(size_t)p * (N + 1) + N] = lds[1023];
}

// K4: scatter src ids into CSR slots
__global__ void k4_scatter(const int* __restrict__ src, const int* __restrict__ dst,
                           int* __restrict__ cursor, int* __restrict__ csr,
                           int E, int N) {
    int p = blockIdx.y;
    int i = blockIdx.x * 256 + threadIdx.x;
    if (i < E) {
        int dv = dst[(size_t)p * E + i];
        int pos = atomicAdd(&cursor[(size_t)p * N + dv], 1);
        csr[(size_t)p * E + pos] = src[(size_t)p * E + i];
    }
}

// K5: per-(node,path) single-pass softmax aggregation (scores bounded, no max shift).
// Lane l owns cols 2l,2l+1 (head hd=l>>4); one float2 feat gather per edge.
__global__ __launch_bounds__(256) void k5_aggregate(const float* __restrict__ feat, const float* __restrict__ el,
                             const float* __restrict__ er, const float* __restrict__ bias,
                             const int* __restrict__ offs, const int* __restrict__ csr,
                             float* __restrict__ z, int N, int E) {
    int w = threadIdx.x >> 6, l = threadIdx.x & 63;
    int n = blockIdx.x * 4 + w;
    int p = blockIdx.y;
    if (n >= N) return;
    int hd = l >> 4;
    int c0 = 2 * l;
    size_t eb = ((size_t)p * N + n) * HH;
    float r = er[eb + hd];
    int j0 = offs[(size_t)p * (N + 1) + n];
    int j1 = offs[(size_t)p * (N + 1) + n + 1];
    const int* cs = csr + (size_t)p * E;
    const float* elp = el + (size_t)p * N * HH;
    const float* fp = feat + (size_t)p * N * FF;
    float acc0 = 0.f, acc1 = 0.f, sumw = 0.f;
    for (int base = j0; base < j1; base += 64) {
        int rem = j1 - base;
        int cnt = rem > 64 ? 64 : rem;
        int mysn = (l < cnt) ? cs[base + l] : 0;   // coalesced batch load of edge srcs
        int tt = 0;
        for (; tt + 2 <= cnt; tt += 2) {
            int sa = __shfl(mysn, tt);
            int sb = __shfl(mysn, tt + 1);
            float ea = elp[(size_t)sa * HH + hd] + r;
            float eb2 = elp[(size_t)sb * HH + hd] + r;
            float2 fa = *(const float2*)&fp[(size_t)sa * FF + c0];
            float2 fb = *(const float2*)&fp[(size_t)sb * FF + c0];
            ea = fmaxf(ea, NEG_SLOPE * ea);
            eb2 = fmaxf(eb2, NEG_SLOPE * eb2);
            float wa = __expf(ea);
            float wb = __expf(eb2);
            acc0 = fmaf(wa, fa.x, acc0);
            acc1 = fmaf(wa, fa.y, acc1);
            sumw += wa;
            acc0 = fmaf(wb, fb.x, acc0);
            acc1 = fmaf(wb, fb.y, acc1);
            sumw += wb;
        }
        if (tt < cnt) {
            int sa = __shfl(mysn, tt);
            float ea = elp[(size_t)sa * HH + hd] + r;
            float2 fa = *(const float2*)&fp[(size_t)sa * FF + c0];
            ea = fmaxf(ea, NEG_SLOPE * ea);
            float wa = __expf(ea);
            acc0 = fmaf(wa, fa.x, acc0);
            acc1 = fmaf(wa, fa.y, acc1);
            sumw += wa;
        }
    }
    float inv = 1.f / sumw;   // self-loops guarantee sumw > 0
    float2 bv = *(const float2*)&bias[p * FF + c0];
    float z0 = acc0 * inv + bv.x;
    float z1 = acc1 * inv + bv.y;
    z0 = z0 > 0.f ? z0 : __expf(z0) - 1.f;
    z1 = z1 > 0.f ? z1 : __expf(z1) - 1.f;
    size_t zb = ((size_t)p * N + n) * FF;
    *(float2*)&z[zb + c0] = make_float2(z0, z1);
}

// K6: s[n,p] = tanh(z @ W1 + b1) @ W2; 8 nodes/wave register tiling.
// Same register-promotion discipline as k1.
__global__ __launch_bounds__(256) void k6_semantic(const float* __restrict__ z, const float* __restrict__ W1,
                            const float* __restrict__ b1, const float* __restrict__ W2,
                            float* __restrict__ partials, int N) {
    __shared__ float wsum[4];
    int t = threadIdx.x;
    int l = t & 63;
    int wu = __builtin_amdgcn_readfirstlane(t >> 6);
    int p = blockIdx.y;
    int nbase = blockIdx.x * 32 + wu * 8;
    int c0 = 2 * l;
    float ssum = 0.f;
    if (nbase < N) {
        int maxoff = N - 1 - nbase;
        size_t roff[8];
#pragma unroll
        for (int nn = 0; nn < 8; ++nn)
            roff[nn] = (size_t)(nn < maxoff ? nn : maxoff) * FF;
        const float* zb = z + ((size_t)p * N + nbase) * FF;
        float2 acc[8];
#pragma unroll
        for (int i = 0; i < 8; ++i) acc[i] = make_float2(0.f, 0.f);
        for (int k = 0; k < FF; k += 4) {
            float2 wv0 = *(const float2*)&W1[(k + 0) * FF + c0];
            float2 wv1 = *(const float2*)&W1[(k + 1) * FF + c0];
            float2 wv2 = *(const float2*)&W1[(k + 2) * FF + c0];
            float2 wv3 = *(const float2*)&W1[(k + 3) * FF + c0];
#pragma unroll
            for (int nn = 0; nn < 8; ++nn) {
                float4 zv = *(const float4*)&zb[roff[nn] + k];   // wave-uniform -> s_load
                acc[nn].x = fmaf(zv.x, wv0.x, acc[nn].x);
                acc[nn].y = fmaf(zv.x, wv0.y, acc[nn].y);
                acc[nn].x = fmaf(zv.y, wv1.x, acc[nn].x);
                acc[nn].y = fmaf(zv.y, wv1.y, acc[nn].y);
                acc[nn].x = fmaf(zv.z, wv2.x, acc[nn].x);
                acc[nn].y = fmaf(zv.z, wv2.y, acc[nn].y);
                acc[nn].x = fmaf(zv.w, wv3.x, acc[nn].x);
                acc[nn].y = fmaf(zv.w, wv3.y, acc[nn].y);
            }
        }
        float2 b1v = *(const float2*)&b1[c0];
        float2 w2v = *(const float2*)&W2[c0];
#pragma unroll
        for (int nn = 0; nn < 8; ++nn) {
            bool valid = nn <= maxoff;
            float a0 = acc[nn].x + b1v.x;
            float a1 = acc[nn].y + b1v.y;
            // tanh(x) = 1 - 2/(exp(2x)+1)  (safe at +/-inf)
            float e0 = __expf(2.f * a0);
            float e1 = __expf(2.f * a1);
            float t0 = 1.f - 2.f * __builtin_amdgcn_rcpf(e0 + 1.f);
            float t1 = 1.f - 2.f * __builtin_amdgcn_rcpf(e1 + 1.f);
            ssum += valid ? (t0 * w2v.x + t1 * w2v.y) : 0.f;
        }
    }
    for (int off = 32; off >= 1; off >>= 1) ssum += __shfl_xor(ssum, off);
    if (l == 0) wsum[wu] = ssum;
    __syncthreads();
    if (t == 0)
        partials[(size_t)p * gridDim.x + blockIdx.x] = wsum[0] + wsum[1] + wsum[2] + wsum[3];
}

// K7: reduce partials -> w[p] mean -> beta softmax. one block, 3 waves.
__global__ void k7_beta(const float* __restrict__ partials, float* __restrict__ beta,
                        int nblk, int N) {
    __shared__ float wl[3];
    int p = threadIdx.x >> 6, l = threadIdx.x & 63;
    float s = 0.f;
    for (int i = l; i < nblk; i += 64) s += partials[(size_t)p * nblk + i];
    for (int off = 32; off >= 1; off >>= 1) s += __shfl_xor(s, off);
    if (l == 0) wl[p] = s / (float)N;
    __syncthreads();
    if (threadIdx.x == 0) {
        float m = fmaxf(wl[0], fmaxf(wl[1], wl[2]));
        float e0 = __expf(wl[0] - m), e1 = __expf(wl[1] - m), e2 = __expf(wl[2] - m);
        float inv = 1.f / (e0 + e1 + e2);
        beta[0] = e0 * inv; beta[1] = e1 * inv; beta[2] = e2 * inv;
    }
}

// K8: out[n,:] = sum_p beta[p] * z[p][n,:]
__global__ void k8_combine(const float* __restrict__ z, const float* __restrict__ beta,
                           float* __restrict__ out, int N) {
    size_t i = (size_t)blockIdx.x * 256 + threadIdx.x;
    size_t tot = (size_t)N * FF;
    if (i < tot) {
        float b0 = beta[0], b1 = beta[1], b2 = beta[2];
        out[i] = b0 * z[i] + b1 * z[tot + i] + b2 * z[2 * tot + i];
    }
}

extern "C" void kernel_launch(void* const* d_in, const int* in_sizes, int n_in,
                              void* d_out, int out_size, void* d_ws, size_t ws_size,
                              hipStream_t stream) {
    const float* h    = (const float*)d_in[0];
    const float* W    = (const float*)d_in[1];
    const float* al   = (const float*)d_in[2];
    const float* ar   = (const float*)d_in[3];
    const float* bias = (const float*)d_in[4];
    const float* W1   = (const float*)d_in[5];
    const float* b1   = (const float*)d_in[6];
    const float* W2   = (const float*)d_in[7];
    const int*   src  = (const int*)d_in[8];
    const int*   dst  = (const int*)d_in[9];
    float* out = (float*)d_out;

    int N = in_sizes[0] / INF_;
    int E = in_sizes[8] / PP;

    char* ws = (char*)d_ws;
    size_t off = 0;
    auto take = [&](size_t bytes) -> void* {
        off = (off + 255) & ~(size_t)255;
        void* ptr = ws + off;
        off += bytes;
        return ptr;
    };
    float* feat     = (float*)take((size_t)PP * N * FF * sizeof(float));
    float* z        = (float*)take((size_t)PP * N * FF * sizeof(float));
    float* el       = (float*)take((size_t)PP * N * HH * sizeof(float));
    float* er       = (float*)take((size_t)PP * N * HH * sizeof(float));
    int*   counts   = (int*)take((size_t)PP * N * sizeof(int));
    int*   offs     = (int*)take((size_t)PP * (N + 1) * sizeof(int));
    int*   cursor   = (int*)take((size_t)PP * N * sizeof(int));
    int*   csr      = (int*)take((size_t)PP * E * sizeof(int));
    int    nblk32   = (N + 31) / 32;
    int    nblk4    = (N + 3) / 4;
    float* partials = (float*)take((size_t)PP * nblk32 * sizeof(float));
    float* betap    = (float*)take(16);
    (void)ws_size; (void)n_in; (void)out_size;

    hipMemsetAsync(counts, 0, (size_t)PP * N * sizeof(int), stream);

    dim3 gTile(nblk32, PP);
    dim3 gNode(nblk4, PP);
    dim3 gEdge((E + 255) / 256, PP);

    k1_gemm<<<gTile, 256, 0, stream>>>(h, W, al, ar, feat, el, er, N);
    k2_hist<<<gEdge, 256, 0, stream>>>(dst, counts, E, N);
    k3_scan<<<PP, 1024, 0, stream>>>(counts, offs, cursor, N);
    k4_scatter<<<gEdge, 256, 0, stream>>>(src, dst, cursor, csr, E, N);
    k5_aggregate<<<gNode, 256, 0, stream>>>(feat, el, er, bias, offs, csr, z, N, E);
    k6_semantic<<<gTile, 256, 0, stream>>>(z, W1, b1, W2, partials, N);
    k7_beta<<<1, 192, 0, stream>>>(partials, betap, nblk32, N);
    k8_combine<<<(int)(((size_t)N * FF + 255) / 256), 256, 0, stream>>>(z, betap, out, N);
}

// Round 4
// 754.065 us; speedup vs baseline: 2.1038x; 1.1842x over previous
//
#include <hip/hip_runtime.h>
#include <math.h>

#define PP 3
#define HH 4
#define DD 32
#define FF 128   // H*D
#define INF_ 128 // input feature dim
#define NEG_SLOPE 0.2f
#define NPART 8      // dst partitions ~ XCDs
#define K4CHUNK 8192 // edges per scatter block

__device__ __forceinline__ unsigned int bf16pair(float x, float y) {
    unsigned int a = __float_as_uint(x);
    unsigned int b = __float_as_uint(y);
    a = (a + 0x7FFFu + ((a >> 16) & 1u)) >> 16;   // RNE round to bf16
    b = (b + 0x7FFFu + ((b >> 16) & 1u)) >> 16;
    return a | (b << 16);
}

// K1: feat[p] = h @ W[p] (stored bf16-packed); el/er reductions fp32.
// 4 waves/block, 8 nodes/wave, lane l owns cols 2l,2l+1. acc[] kept in VGPRs
// (all indices compile-time constant; tail rows clamped, stores predicated).
__global__ __launch_bounds__(256) void k1_gemm(const float* __restrict__ h, const float* __restrict__ W,
                        const float* __restrict__ al, const float* __restrict__ ar,
                        unsigned int* __restrict__ featb, float* __restrict__ el,
                        float* __restrict__ er, int N) {
    int l = threadIdx.x & 63;
    int wu = __builtin_amdgcn_readfirstlane(threadIdx.x >> 6);
    int p = blockIdx.y;
    int nbase = blockIdx.x * 32 + wu * 8;
    if (nbase >= N) return;
    const float* Wp = W + (size_t)p * INF_ * FF;
    int c0 = 2 * l;
    int maxoff = N - 1 - nbase;
    size_t roff[8];
#pragma unroll
    for (int nn = 0; nn < 8; ++nn)
        roff[nn] = (size_t)(nn < maxoff ? nn : maxoff) * INF_;
    const float* hb = h + (size_t)nbase * INF_;

    float2 acc[8];
#pragma unroll
    for (int i = 0; i < 8; ++i) acc[i] = make_float2(0.f, 0.f);

    for (int k = 0; k < INF_; k += 4) {
        float2 wv0 = *(const float2*)&Wp[(k + 0) * FF + c0];
        float2 wv1 = *(const float2*)&Wp[(k + 1) * FF + c0];
        float2 wv2 = *(const float2*)&Wp[(k + 2) * FF + c0];
        float2 wv3 = *(const float2*)&Wp[(k + 3) * FF + c0];
#pragma unroll
        for (int nn = 0; nn < 8; ++nn) {
            float4 hv = *(const float4*)&hb[roff[nn] + k];   // wave-uniform -> s_load
            acc[nn].x = fmaf(hv.x, wv0.x, acc[nn].x);
            acc[nn].y = fmaf(hv.x, wv0.y, acc[nn].y);
            acc[nn].x = fmaf(hv.y, wv1.x, acc[nn].x);
            acc[nn].y = fmaf(hv.y, wv1.y, acc[nn].y);
            acc[nn].x = fmaf(hv.z, wv2.x, acc[nn].x);
            acc[nn].y = fmaf(hv.z, wv2.y, acc[nn].y);
            acc[nn].x = fmaf(hv.w, wv3.x, acc[nn].x);
            acc[nn].y = fmaf(hv.w, wv3.y, acc[nn].y);
        }
    }

    int hd = l >> 4;
    int d0 = (2 * l) & 31;
    float2 alv = *(const float2*)&al[(p * HH + hd) * DD + d0];
    float2 arv = *(const float2*)&ar[(p * HH + hd) * DD + d0];
#pragma unroll
    for (int nn = 0; nn < 8; ++nn) {
        bool valid = nn <= maxoff;
        int n = nbase + nn;
        float pl = acc[nn].x * alv.x + acc[nn].y * alv.y;
        float pr = acc[nn].x * arv.x + acc[nn].y * arv.y;
        for (int off = 8; off >= 1; off >>= 1) {
            pl += __shfl_xor(pl, off);
            pr += __shfl_xor(pr, off);
        }
        if (valid) {
            featb[((size_t)p * N + n) * 64 + l] = bf16pair(acc[nn].x, acc[nn].y);
            if ((l & 15) == 0) {
                size_t eb = ((size_t)p * N + n) * HH + hd;
                el[eb] = pl;
                er[eb] = pr;
            }
        }
    }
}

// K2: histogram of dst degrees
__global__ void k2_hist(const int* __restrict__ dst, int* __restrict__ counts,
                        int E, int N) {
    int p = blockIdx.y;
    int i = blockIdx.x * 256 + threadIdx.x;
    if (i < E) atomicAdd(&counts[(size_t)p * N + dst[(size_t)p * E + i]], 1);
}

// K3: exclusive prefix sum over counts -> offs (N+1), cursor copy. one block per path.
__global__ __launch_bounds__(1024) void k3_scan(const int* __restrict__ counts,
                                                int* __restrict__ offs,
                                                int* __restrict__ cursor, int N) {
    __shared__ int lds[1024];
    int p = blockIdx.x;
    int t = threadIdx.x;
    int chunk = (N + 1023) / 1024;
    int base = t * chunk;
    int end = base + chunk; if (end > N) end = N; if (base > N) base = N;
    int s = 0;
    for (int i = base; i < end; ++i) s += counts[(size_t)p * N + i];
    lds[t] = s;
    __syncthreads();
    for (int off = 1; off < 1024; off <<= 1) {
        int v = (t >= off) ? lds[t - off] : 0;
        __syncthreads();
        lds[t] += v;
        __syncthreads();
    }
    int run = lds[t] - s;  // exclusive prefix for this thread
    for (int i = base; i < end; ++i) {
        offs[(size_t)p * (N + 1) + i] = run;
        cursor[(size_t)p * N + i] = run;
        run += counts[(size_t)p * N + i];
    }
    if (t == 0) offs[(size_t)p * (N + 1) + N] = lds[1023];
}

// K4: scatter src ids into CSR slots, dst-partitioned so each partition's
// contiguous csr slice is written by one stride-8 block family (-> one XCD's
// L2 under round-robin dispatch) => write-combining instead of 16x line
// amplification. Each block re-reads its edge chunk (L3-resident).
__global__ __launch_bounds__(256) void k4_scatter(const int* __restrict__ src, const int* __restrict__ dst,
                           int* __restrict__ cursor, int* __restrict__ csr,
                           int E, int N) {
    int p = blockIdx.y;
    int part = blockIdx.x & (NPART - 1);
    int chunk = blockIdx.x >> 3;
    int pw = (N + NPART - 1) / NPART;
    int lo = part * pw;
    int hi = lo + pw; if (hi > N) hi = N;
    int base = chunk * K4CHUNK;
    int end = base + K4CHUNK; if (end > E) end = E;
    const int* sp = src + (size_t)p * E;
    const int* dp = dst + (size_t)p * E;
    int* cur = cursor + (size_t)p * N;
    int* cp = csr + (size_t)p * E;
    if ((E & 3) == 0) {
        for (int i = base + 4 * (int)threadIdx.x; i < end; i += 1024) {
            int4 d4 = *(const int4*)&dp[i];
            int4 s4 = *(const int4*)&sp[i];
            if (d4.x >= lo && d4.x < hi) cp[atomicAdd(&cur[d4.x], 1)] = s4.x;
            if (d4.y >= lo && d4.y < hi) cp[atomicAdd(&cur[d4.y], 1)] = s4.y;
            if (d4.z >= lo && d4.z < hi) cp[atomicAdd(&cur[d4.z], 1)] = s4.z;
            if (d4.w >= lo && d4.w < hi) cp[atomicAdd(&cur[d4.w], 1)] = s4.w;
        }
    } else {
        for (int i = base + (int)threadIdx.x; i < end; i += 256) {
            int d = dp[i];
            if (d >= lo && d < hi) cp[atomicAdd(&cur[d], 1)] = sp[i];
        }
    }
}

// K5: per-(node,path) single-pass softmax aggregation; feat gathered as bf16
// pairs (half the gather traffic). Lane l owns cols 2l,2l+1 (head hd=l>>4).
__global__ __launch_bounds__(256) void k5_aggregate(const unsigned int* __restrict__ featb, const float* __restrict__ el,
                             const float* __restrict__ er, const float* __restrict__ bias,
                             const int* __restrict__ offs, const int* __restrict__ csr,
                             float* __restrict__ z, int N, int E) {
    int w = threadIdx.x >> 6, l = threadIdx.x & 63;
    int n = blockIdx.x * 4 + w;
    int p = blockIdx.y;
    if (n >= N) return;
    int hd = l >> 4;
    int c0 = 2 * l;
    size_t eb = ((size_t)p * N + n) * HH;
    float r = er[eb + hd];
    int j0 = offs[(size_t)p * (N + 1) + n];
    int j1 = offs[(size_t)p * (N + 1) + n + 1];
    const int* cs = csr + (size_t)p * E;
    const float* elp = el + (size_t)p * N * HH;
    const unsigned int* fp = featb + (size_t)p * N * 64;
    float acc0 = 0.f, acc1 = 0.f, sumw = 0.f;
    for (int base = j0; base < j1; base += 64) {
        int rem = j1 - base;
        int cnt = rem > 64 ? 64 : rem;
        int mysn = (l < cnt) ? cs[base + l] : 0;   // coalesced batch load of edge srcs
        int tt = 0;
        for (; tt + 2 <= cnt; tt += 2) {
            int sa = __shfl(mysn, tt);
            int sb = __shfl(mysn, tt + 1);
            float ea = elp[(size_t)sa * HH + hd] + r;
            float eb2 = elp[(size_t)sb * HH + hd] + r;
            unsigned int va = fp[(size_t)sa * 64 + l];
            unsigned int vb = fp[(size_t)sb * 64 + l];
            ea = fmaxf(ea, NEG_SLOPE * ea);
            eb2 = fmaxf(eb2, NEG_SLOPE * eb2);
            float wa = __expf(ea);
            float wb = __expf(eb2);
            acc0 = fmaf(wa, __uint_as_float(va << 16), acc0);
            acc1 = fmaf(wa, __uint_as_float(va & 0xFFFF0000u), acc1);
            sumw += wa;
            acc0 = fmaf(wb, __uint_as_float(vb << 16), acc0);
            acc1 = fmaf(wb, __uint_as_float(vb & 0xFFFF0000u), acc1);
            sumw += wb;
        }
        if (tt < cnt) {
            int sa = __shfl(mysn, tt);
            float ea = elp[(size_t)sa * HH + hd] + r;
            unsigned int va = fp[(size_t)sa * 64 + l];
            ea = fmaxf(ea, NEG_SLOPE * ea);
            float wa = __expf(ea);
            acc0 = fmaf(wa, __uint_as_float(va << 16), acc0);
            acc1 = fmaf(wa, __uint_as_float(va & 0xFFFF0000u), acc1);
            sumw += wa;
        }
    }
    float inv = 1.f / sumw;   // self-loops guarantee sumw > 0
    float2 bv = *(const float2*)&bias[p * FF + c0];
    float z0 = acc0 * inv + bv.x;
    float z1 = acc1 * inv + bv.y;
    z0 = z0 > 0.f ? z0 : __expf(z0) - 1.f;
    z1 = z1 > 0.f ? z1 : __expf(z1) - 1.f;
    size_t zb = ((size_t)p * N + n) * FF;
    *(float2*)&z[zb + c0] = make_float2(z0, z1);
}

// K6: s[n,p] = tanh(z @ W1 + b1) @ W2; 8 nodes/wave register tiling.
__global__ __launch_bounds__(256) void k6_semantic(const float* __restrict__ z, const float* __restrict__ W1,
                            const float* __restrict__ b1, const float* __restrict__ W2,
                            float* __restrict__ partials, int N) {
    __shared__ float wsum[4];
    int t = threadIdx.x;
    int l = t & 63;
    int wu = __builtin_amdgcn_readfirstlane(t >> 6);
    int p = blockIdx.y;
    int nbase = blockIdx.x * 32 + wu * 8;
    int c0 = 2 * l;
    float ssum = 0.f;
    if (nbase < N) {
        int maxoff = N - 1 - nbase;
        size_t roff[8];
#pragma unroll
        for (int nn = 0; nn < 8; ++nn)
            roff[nn] = (size_t)(nn < maxoff ? nn : maxoff) * FF;
        const float* zb = z + ((size_t)p * N + nbase) * FF;
        float2 acc[8];
#pragma unroll
        for (int i = 0; i < 8; ++i) acc[i] = make_float2(0.f, 0.f);
        for (int k = 0; k < FF; k += 4) {
            float2 wv0 = *(const float2*)&W1[(k + 0) * FF + c0];
            float2 wv1 = *(const float2*)&W1[(k + 1) * FF + c0];
            float2 wv2 = *(const float2*)&W1[(k + 2) * FF + c0];
            float2 wv3 = *(const float2*)&W1[(k + 3) * FF + c0];
#pragma unroll
            for (int nn = 0; nn < 8; ++nn) {
                float4 zv = *(const float4*)&zb[roff[nn] + k];   // wave-uniform -> s_load
                acc[nn].x = fmaf(zv.x, wv0.x, acc[nn].x);
                acc[nn].y = fmaf(zv.x, wv0.y, acc[nn].y);
                acc[nn].x = fmaf(zv.y, wv1.x, acc[nn].x);
                acc[nn].y = fmaf(zv.y, wv1.y, acc[nn].y);
                acc[nn].x = fmaf(zv.z, wv2.x, acc[nn].x);
                acc[nn].y = fmaf(zv.z, wv2.y, acc[nn].y);
                acc[nn].x = fmaf(zv.w, wv3.x, acc[nn].x);
                acc[nn].y = fmaf(zv.w, wv3.y, acc[nn].y);
            }
        }
        float2 b1v = *(const float2*)&b1[c0];
        float2 w2v = *(const float2*)&W2[c0];
#pragma unroll
        for (int nn = 0; nn < 8; ++nn) {
            bool valid = nn <= maxoff;
            float a0 = acc[nn].x + b1v.x;
            float a1 = acc[nn].y + b1v.y;
            // tanh(x) = 1 - 2/(exp(2x)+1)  (safe at +/-inf)
            float e0 = __expf(2.f * a0);
            float e1 = __expf(2.f * a1);
            float t0 = 1.f - 2.f * __builtin_amdgcn_rcpf(e0 + 1.f);
            float t1 = 1.f - 2.f * __builtin_amdgcn_rcpf(e1 + 1.f);
            ssum += valid ? (t0 * w2v.x + t1 * w2v.y) : 0.f;
        }
    }
    for (int off = 32; off >= 1; off >>= 1) ssum += __shfl_xor(ssum, off);
    if (l == 0) wsum[wu] = ssum;
    __syncthreads();
    if (t == 0)
        partials[(size_t)p * gridDim.x + blockIdx.x] = wsum[0] + wsum[1] + wsum[2] + wsum[3];
}

// K7: reduce partials -> w[p] mean -> beta softmax. one block, 3 waves.
__global__ void k7_beta(const float* __restrict__ partials, float* __restrict__ beta,
                        int nblk, int N) {
    __shared__ float wl[3];
    int p = threadIdx.x >> 6, l = threadIdx.x & 63;
    float s = 0.f;
    for (int i = l; i < nblk; i += 64) s += partials[(size_t)p * nblk + i];
    for (int off = 32; off >= 1; off >>= 1) s += __shfl_xor(s, off);
    if (l == 0) wl[p] = s / (float)N;
    __syncthreads();
    if (threadIdx.x == 0) {
        float m = fmaxf(wl[0], fmaxf(wl[1], wl[2]));
        float e0 = __expf(wl[0] - m), e1 = __expf(wl[1] - m), e2 = __expf(wl[2] - m);
        float inv = 1.f / (e0 + e1 + e2);
        beta[0] = e0 * inv; beta[1] = e1 * inv; beta[2] = e2 * inv;
    }
}

// K8: out[n,:] = sum_p beta[p] * z[p][n,:]
__global__ void k8_combine(const float* __restrict__ z, const float* __restrict__ beta,
                           float* __restrict__ out, int N) {
    size_t i = (size_t)blockIdx.x * 256 + threadIdx.x;
    size_t tot = (size_t)N * FF;
    if (i < tot) {
        float b0 = beta[0], b1 = beta[1], b2 = beta[2];
        out[i] = b0 * z[i] + b1 * z[tot + i] + b2 * z[2 * tot + i];
    }
}

extern "C" void kernel_launch(void* const* d_in, const int* in_sizes, int n_in,
                              void* d_out, int out_size, void* d_ws, size_t ws_size,
                              hipStream_t stream) {
    const float* h    = (const float*)d_in[0];
    const float* W    = (const float*)d_in[1];
    const float* al   = (const float*)d_in[2];
    const float* ar   = (const float*)d_in[3];
    const float* bias = (const float*)d_in[4];
    const float* W1   = (const float*)d_in[5];
    const float* b1   = (const float*)d_in[6];
    const float* W2   = (const float*)d_in[7];
    const int*   src  = (const int*)d_in[8];
    const int*   dst  = (const int*)d_in[9];
    float* out = (float*)d_out;

    int N = in_sizes[0] / INF_;
    int E = in_sizes[8] / PP;

    char* ws = (char*)d_ws;
    size_t off = 0;
    auto take = [&](size_t bytes) -> void* {
        off = (off + 255) & ~(size_t)255;
        void* ptr = ws + off;
        off += bytes;
        return ptr;
    };
    unsigned int* featb = (unsigned int*)take((size_t)PP * N * 64 * sizeof(unsigned int));
    float* z        = (float*)take((size_t)PP * N * FF * sizeof(float));
    float* el       = (float*)take((size_t)PP * N * HH * sizeof(float));
    float* er       = (float*)take((size_t)PP * N * HH * sizeof(float));
    int*   counts   = (int*)take((size_t)PP * N * sizeof(int));
    int*   offs     = (int*)take((size_t)PP * (N + 1) * sizeof(int));
    int*   cursor   = (int*)take((size_t)PP * N * sizeof(int));
    int*   csr      = (int*)take((size_t)PP * E * sizeof(int));
    int    nblk32   = (N + 31) / 32;
    int    nblk4    = (N + 3) / 4;
    float* partials = (float*)take((size_t)PP * nblk32 * sizeof(float));
    float* betap    = (float*)take(16);
    (void)ws_size; (void)n_in; (void)out_size;

    hipMemsetAsync(counts, 0, (size_t)PP * N * sizeof(int), stream);

    dim3 gTile(nblk32, PP);
    dim3 gNode(nblk4, PP);
    dim3 gEdge((E + 255) / 256, PP);
    dim3 gScat(((E + K4CHUNK - 1) / K4CHUNK) * NPART, PP);

    k1_gemm<<<gTile, 256, 0, stream>>>(h, W, al, ar, featb, el, er, N);
    k2_hist<<<gEdge, 256, 0, stream>>>(dst, counts, E, N);
    k3_scan<<<PP, 1024, 0, stream>>>(counts, offs, cursor, N);
    k4_scatter<<<gScat, 256, 0, stream>>>(src, dst, cursor, csr, E, N);
    k5_aggregate<<<gNode, 256, 0, stream>>>(featb, el, er, bias, offs, csr, z, N, E);
    k6_semantic<<<gTile, 256, 0, stream>>>(z, W1, b1, W2, partials, N);
    k7_beta<<<1, 192, 0, stream>>>(partials, betap, nblk32, N);
    k8_combine<<<(int)(((size_t)N * FF + 255) / 256), 256, 0, stream>>>(z, betap, out, N);
}